// Round 24
// baseline (323.522 us; speedup 1.0000x reference)
//
#include <hip/hip_runtime.h>
#include <stdint.h>

typedef float f32x4 __attribute__((ext_vector_type(4)));
typedef short s16x8 __attribute__((ext_vector_type(8)));
typedef unsigned u32x2 __attribute__((ext_vector_type(2)));
typedef unsigned u32x4 __attribute__((ext_vector_type(4)));

#define B_SZ 256
#define A_RG 196
#define DVD  2048
#define RNN  1024
#define H_SZ 512
#define NKT  (DVD / 32)       // 64 K-tiles

__device__ __forceinline__ unsigned cvt2(float a, float b) {
    unsigned r;
    asm("v_cvt_pk_bf16_f32 %0, %1, %2" : "=v"(r) : "v"(a), "v"(b));
    return r;
}

// ---------------------------------------------------------------------------
// Kernel 1 (R22-verified): W_v [2048,512] fp32 -> Wt4 bf16, MFMA-B-fragment
// order with packed 16B stores.
// ---------------------------------------------------------------------------
__global__ __launch_bounds__(256) void k_prepW(const float* __restrict__ Wv,
                                               unsigned short* __restrict__ Wt4) {
    __shared__ float tile[64][65];
    int kb = blockIdx.x >> 3, ct = blockIdx.x & 7;
    int k0 = kb * 64, c0 = ct * 64;
    int t = threadIdx.x;
    int cl = t & 63, rq = t >> 6;
#pragma unroll
    for (int i = 0; i < 16; ++i) {
        int r = rq * 16 + i;
        tile[r][cl] = Wv[(size_t)(k0 + r) * H_SZ + c0 + cl];
    }
    __syncthreads();
#pragma unroll
    for (int half = 0; half < 2; ++half) {
        int cid = half * 256 + t;
        int gg = cid >> 6, cr = cid & 63;
        int col = c0 + cr;
        int kt = kb * 2 + (gg >> 2), g = gg & 3;
        int f = col >> 4, lr = col & 15;
        size_t slot = ((size_t)(kt * 32 + f) * 64 + g * 16 + lr);
        u32x4 pk;
#pragma unroll
        for (int p = 0; p < 4; ++p)
            pk[p] = cvt2(tile[gg * 8 + 2 * p][cr], tile[gg * 8 + 2 * p + 1][cr]);
        *(u32x4*)(Wt4 + slot * 8) = pk;
    }
}

// ---------------------------------------------------------------------------
// Kernel 2 (R22-verified): base[b,h] = h_att@W_ha + prev_h2@W_hv + biases.
// ---------------------------------------------------------------------------
__global__ __launch_bounds__(256) void k_base(const float* __restrict__ h_att,
                                              const float* __restrict__ prev_h2,
                                              const float* __restrict__ W_ha,
                                              const float* __restrict__ b_ha,
                                              const float* __restrict__ W_hv,
                                              const float* __restrict__ b_hv,
                                              const float* __restrict__ b_v,
                                              float* __restrict__ base_g) {
    __shared__ float ha_s[RNN];
    __shared__ float pv_s[RNN];
    __shared__ float redA[128];
    __shared__ float redV[128];

    const int hg = blockIdx.x;
    const int b  = blockIdx.y;
    const int t  = threadIdx.x;

    for (int i = t; i < RNN; i += 256) {
        ha_s[i] = h_att[(size_t)b * RNN + i];
        pv_s[i] = prev_h2[(size_t)b * RNN + i];
    }
    __syncthreads();

    const int h  = hg * 128 + (t & 127);
    const int ks = t >> 7;
    const int kb = ks * 512;
    const float* Wa = W_ha + (size_t)kb * H_SZ + h;
    const float* Wv = W_hv + (size_t)kb * H_SZ + h;

    float aA = 0.f, aV = 0.f;
#pragma unroll 8
    for (int k = 0; k < 512; ++k) {
        aA = fmaf(ha_s[kb + k], Wa[(size_t)k * H_SZ], aA);
        aV = fmaf(pv_s[kb + k], Wv[(size_t)k * H_SZ], aV);
    }

    if (ks == 1) { redA[t & 127] = aA; redV[t & 127] = aV; }
    __syncthreads();
    if (ks == 0) {
        float s = aA + aV + redA[t] + redV[t] + b_ha[h] + b_hv[h] + b_v[h];
        base_g[(size_t)b * H_SZ + h] = s;
    }
}

// ---------------------------------------------------------------------------
// Kernel 3 (fused, R24 = R22 best-measured loop, minus setprio [m190:
// setprio hurts lockstep GEMM], plus tile1-prologue loads hoisted above
// tile0's V phase [kills the one exposed prologue HBM latency]).
// 1024 thr = 16 waves (2M x 8N), wave 64x64, acc[4][4]=64 AGPR, 128-reg
// cap. A: bf16 LDS dbuf (verified swizzle); B: register-direct 4 frags
// from L2-hot fragment-packed Wt4, WAR reloads; 1 barrier/kstep.
// Score -> online softmax -> V accumulate (R13/R16/R22-verified).
// ---------------------------------------------------------------------------
__global__ __launch_bounds__(1024, 4) void k_fused(const float* __restrict__ imgs,
                                                   const unsigned short* __restrict__ Wt4,
                                                   const float* __restrict__ base_g,
                                                   const float* __restrict__ W_f,
                                                   float* __restrict__ out) {
    __shared__ __align__(16) short A_s[2][128 * 32];   // 2 x 8 KB
    __shared__ float att_part[8][128];
    __shared__ float e_s[128];
    __shared__ float scal_r;
    __shared__ float scal_l;

    const int b = blockIdx.x;
    const int t = threadIdx.x;
    const int lane = t & 63, w = t >> 6;
    const int wm = w >> 3, wn = w & 7;           // 2M x 8N wave grid
    const int lr = lane & 15, g = lane >> 4;

    const float* imgb = imgs + (size_t)b * A_RG * DVD;
    const char* Bp = (const char*)Wt4 + ((size_t)(wn * 4) * 64 + lane) * 16;

    float o0 = 0.f, o1 = 0.f;           // thread owns out cols 2t, 2t+1
    float m_run = -1e30f, l_run = 0.f;  // live in wave 0

    // ---- A staging map: thread -> local row t>>3, chunk t&7 (4 floats) ----
    const int arow = t >> 3, ac = t & 7;
    const unsigned awr = (unsigned)(arow * 64 +
        ((((ac >> 1) ^ ((arow ^ (arow >> 2)) & 3)) << 4) | ((ac & 1) << 3)));

    // ---- A fragment read addresses ----
    unsigned ard[4];
#pragma unroll
    for (int mf = 0; mf < 4; ++mf) {
        int r = wm * 64 + mf * 16 + lr;
        ard[mf] = (unsigned)(r * 64 + ((g ^ ((r ^ (r >> 2)) & 3)) << 4));
    }

    f32x4 rA;
    s16x8 bR[4];

    // A source for tile at (clamped); recomputed per tile
    const float* Ag0 = imgb + (size_t)min(arow, A_RG - 1) * DVD + ac * 4;
    const float* Ag1 = imgb + (size_t)min(128 + arow, A_RG - 1) * DVD + ac * 4;

    auto ldB = [&](int kt) {
        const char* p = Bp + (size_t)kt * 32768;
#pragma unroll
        for (int n = 0; n < 4; ++n)
            bR[n] = *(const s16x8*)(p + n * 1024);
    };
    auto wrA = [&](int buf) {
        u32x2 pk;
        pk[0] = cvt2(rA[0], rA[1]);
        pk[1] = cvt2(rA[2], rA[3]);
        *(u32x2*)((char*)A_s[buf] + awr) = pk;   // counted vmcnt wait on rA
    };

    // ---- tile0 prologue: B(0), A(0)->buf0 ----
    ldB(0);
    rA = *(const f32x4*)(Ag0);
    wrA(0);
    asm volatile("s_waitcnt lgkmcnt(0)" ::: "memory");
    __builtin_amdgcn_sched_barrier(0);
    __builtin_amdgcn_s_barrier();

    for (int at = 0; at < 2; ++at) {
        const bool last = (at == 1);
        const int m0 = at * 128;
        const float* Ag = last ? Ag1 : Ag0;

        f32x4 acc[4][4] = {};
        s16x8 aF[4];

        // ---- K loop: 1 barrier/kstep (R16/R22-proven), no setprio ----
        for (int kt = 0; kt < NKT; ++kt) {
            if (kt + 1 < NKT)
                rA = *(const f32x4*)(Ag + (size_t)(kt + 1) * 32);  // HBM
            const char* Ac = (const char*)A_s[kt & 1];
#pragma unroll
            for (int mf = 0; mf < 4; ++mf)
                aF[mf] = *(const s16x8*)(Ac + ard[mf]);
#pragma unroll
            for (int mf = 0; mf < 4; ++mf)
#pragma unroll
                for (int n = 0; n < 4; ++n)
                    acc[mf][n] = __builtin_amdgcn_mfma_f32_16x16x32_bf16(
                        aF[mf], bR[n], acc[mf][n], 0, 0, 0);
            if (kt + 1 < NKT) {
                ldB(kt + 1);                         // WAR reload, L2/L1
                wrA((kt + 1) & 1);                   // waits rA (auto vmcnt)
                asm volatile("s_waitcnt lgkmcnt(0)" ::: "memory");
                __builtin_amdgcn_sched_barrier(0);
                __builtin_amdgcn_s_barrier();
            }
        }

        // ---- score epilogue: this wave's 64 cols -> att_part[wn][row] ----
        {
            float wfv[4], bs[4];
#pragma unroll
            for (int n = 0; n < 4; ++n) {
                int col = wn * 64 + n * 16 + lr;
                wfv[n] = W_f[col];
                bs[n] = base_g[(size_t)b * H_SZ + col];
            }
#pragma unroll
            for (int mf = 0; mf < 4; ++mf) {
                float pj[4] = {0.f, 0.f, 0.f, 0.f};
#pragma unroll
                for (int n = 0; n < 4; ++n) {
                    float a0 = fmaxf(acc[mf][n][0] + bs[n], 0.f);
                    float a1 = fmaxf(acc[mf][n][1] + bs[n], 0.f);
                    float a2 = fmaxf(acc[mf][n][2] + bs[n], 0.f);
                    float a3 = fmaxf(acc[mf][n][3] + bs[n], 0.f);
                    pj[0] = fmaf(a0, wfv[n], pj[0]);
                    pj[1] = fmaf(a1, wfv[n], pj[1]);
                    pj[2] = fmaf(a2, wfv[n], pj[2]);
                    pj[3] = fmaf(a3, wfv[n], pj[3]);
                }
#pragma unroll
                for (int j = 0; j < 4; ++j) {
                    float s = pj[j];
                    s += __shfl_xor(s, 1);
                    s += __shfl_xor(s, 2);
                    s += __shfl_xor(s, 4);
                    s += __shfl_xor(s, 8);   // 16 lr-lanes of this row
                    if (lr == 0)
                        att_part[wn][wm * 64 + mf * 16 + g * 4 + j] = s;
                }
            }
        }
        __builtin_amdgcn_s_barrier();

        // ---- wave 0: online-softmax state update ----
        if (w == 0) {
            int gr0 = m0 + lane, gr1 = m0 + lane + 64;
            float s0, s1;
            {
                float a = 0.f, c = 0.f;
#pragma unroll
                for (int q = 0; q < 8; ++q) {
                    a += att_part[q][lane];
                    c += att_part[q][lane + 64];
                }
                s0 = (gr0 < A_RG) ? a : -1e30f;
                s1 = (gr1 < A_RG) ? c : -1e30f;
            }
            float mx = fmaxf(s0, s1);
            for (int d = 1; d < 64; d <<= 1) mx = fmaxf(mx, __shfl_xor(mx, d));
            float m_new = fmaxf(m_run, mx);
            float r = __expf(m_run - m_new);
            float e0 = __expf(s0 - m_new);
            float e1 = __expf(s1 - m_new);
            float es = e0 + e1;
            for (int d = 1; d < 64; d <<= 1) es += __shfl_xor(es, d);
            l_run = l_run * r + es;
            m_run = m_new;
            e_s[lane] = e0;
            e_s[lane + 64] = e1;
            if (lane == 0) {
                scal_r = r;
                if (last) scal_l = l_run;
            }
        }
        __builtin_amdgcn_s_barrier();

        // ---- overlap: issue tile1's prologue loads BEFORE tile0's V phase
        //      (A(0) HBM + B(0) L2 land under the ~600cy V loop; buf0 of
        //      A_s was last read at kstep 62 and is multi-barrier fenced) ----
        if (!last) {
            ldB(0);
            rA = *(const f32x4*)(Ag1);
        }

        // ---- V phase: o = o*r + sum_a e[a] * imgs[b, m0+a, 2t..2t+1] ----
        {
            float r = scal_r;
            o0 *= r; o1 *= r;
            const float2* vb = (const float2*)imgb + t;
            const int AV = last ? (A_RG - 128) : 128;   // 68 or 128
#pragma unroll 4
            for (int a = 0; a < AV; ++a) {
                float e = e_s[a];
                float2 v = vb[(size_t)(m0 + a) * (DVD / 2)];
                o0 = fmaf(e, v.x, o0);
                o1 = fmaf(e, v.y, o1);
            }
        }

        // ---- tile1 prologue completion: write A(0) into buf0, fence ----
        if (!last) {
            wrA(0);                                   // waits rA (counted)
            asm volatile("s_waitcnt lgkmcnt(0)" ::: "memory");
            __builtin_amdgcn_sched_barrier(0);
            __builtin_amdgcn_s_barrier();
        }
    }

    // ---- finalize: out[b, 2t..2t+1] = o / l ----
    float linv = 1.0f / scal_l;
    float2 res = make_float2(o0 * linv, o1 * linv);
    ((float2*)(out + (size_t)b * DVD))[t] = res;
}

// ---------------------------------------------------------------------------
extern "C" void kernel_launch(void* const* d_in, const int* in_sizes, int n_in,
                              void* d_out, int out_size, void* d_ws, size_t ws_size,
                              hipStream_t stream) {
    const float* h_att   = (const float*)d_in[0];
    const float* prev_h2 = (const float*)d_in[1];
    const float* imgs    = (const float*)d_in[2];
    const float* W_v     = (const float*)d_in[3];
    const float* b_v     = (const float*)d_in[4];
    const float* W_ha    = (const float*)d_in[5];
    const float* b_ha    = (const float*)d_in[6];
    const float* W_hv    = (const float*)d_in[7];
    const float* b_hv    = (const float*)d_in[8];
    const float* W_f     = (const float*)d_in[9];
    // d_in[10] = b_f: softmax-invariant additive constant -> unused

    // ws layout: [0,2MB) Wt4 bf16 fragment-packed; [2MB,+512KB) base fp32
    unsigned short* Wt4 = (unsigned short*)d_ws;
    float* base_g = (float*)((char*)d_ws + (size_t)DVD * H_SZ * 2);
    float* out = (float*)d_out;

    hipLaunchKernelGGL(k_prepW, dim3(256), dim3(256), 0, stream, W_v, Wt4);
    hipLaunchKernelGGL(k_base, dim3(4, B_SZ), dim3(256), 0, stream,
                       h_att, prev_h2, W_ha, b_ha, W_hv, b_hv, b_v, base_g);
    hipLaunchKernelGGL(k_fused, dim3(B_SZ), dim3(1024), 0, stream,
                       imgs, Wt4, base_g, W_f, out);
}

// Round 25
// 270.042 us; speedup vs baseline: 1.1980x; 1.1980x over previous
//
#include <hip/hip_runtime.h>
#include <stdint.h>

typedef float f32x4 __attribute__((ext_vector_type(4)));
typedef short s16x8 __attribute__((ext_vector_type(8)));
typedef unsigned u32x2 __attribute__((ext_vector_type(2)));
typedef unsigned u32x4 __attribute__((ext_vector_type(4)));

#define B_SZ 256
#define A_RG 196
#define DVD  2048
#define RNN  1024
#define H_SZ 512
#define NKT  (DVD / 32)       // 64 K-tiles

__device__ __forceinline__ unsigned cvt2(float a, float b) {
    unsigned r;
    asm("v_cvt_pk_bf16_f32 %0, %1, %2" : "=v"(r) : "v"(a), "v"(b));
    return r;
}

// ---------------------------------------------------------------------------
// Kernel 1 (R22-verified): W_v [2048,512] fp32 -> Wt4 bf16, MFMA-B-fragment
// order with packed 16B stores.
// ---------------------------------------------------------------------------
__global__ __launch_bounds__(256) void k_prepW(const float* __restrict__ Wv,
                                               unsigned short* __restrict__ Wt4) {
    __shared__ float tile[64][65];
    int kb = blockIdx.x >> 3, ct = blockIdx.x & 7;
    int k0 = kb * 64, c0 = ct * 64;
    int t = threadIdx.x;
    int cl = t & 63, rq = t >> 6;
#pragma unroll
    for (int i = 0; i < 16; ++i) {
        int r = rq * 16 + i;
        tile[r][cl] = Wv[(size_t)(k0 + r) * H_SZ + c0 + cl];
    }
    __syncthreads();
#pragma unroll
    for (int half = 0; half < 2; ++half) {
        int cid = half * 256 + t;
        int gg = cid >> 6, cr = cid & 63;
        int col = c0 + cr;
        int kt = kb * 2 + (gg >> 2), g = gg & 3;
        int f = col >> 4, lr = col & 15;
        size_t slot = ((size_t)(kt * 32 + f) * 64 + g * 16 + lr);
        u32x4 pk;
#pragma unroll
        for (int p = 0; p < 4; ++p)
            pk[p] = cvt2(tile[gg * 8 + 2 * p][cr], tile[gg * 8 + 2 * p + 1][cr]);
        *(u32x4*)(Wt4 + slot * 8) = pk;
    }
}

// ---------------------------------------------------------------------------
// Kernel 2 (R22-verified): base[b,h] = h_att@W_ha + prev_h2@W_hv + biases.
// grid (4 hg, 256 b) = 1024 blocks, block 256 = 128 h x 2 k-halves.
// ---------------------------------------------------------------------------
__global__ __launch_bounds__(256) void k_base(const float* __restrict__ h_att,
                                              const float* __restrict__ prev_h2,
                                              const float* __restrict__ W_ha,
                                              const float* __restrict__ b_ha,
                                              const float* __restrict__ W_hv,
                                              const float* __restrict__ b_hv,
                                              const float* __restrict__ b_v,
                                              float* __restrict__ base_g) {
    __shared__ float ha_s[RNN];
    __shared__ float pv_s[RNN];
    __shared__ float redA[128];
    __shared__ float redV[128];

    const int hg = blockIdx.x;
    const int b  = blockIdx.y;
    const int t  = threadIdx.x;

    for (int i = t; i < RNN; i += 256) {
        ha_s[i] = h_att[(size_t)b * RNN + i];
        pv_s[i] = prev_h2[(size_t)b * RNN + i];
    }
    __syncthreads();

    const int h  = hg * 128 + (t & 127);
    const int ks = t >> 7;
    const int kb = ks * 512;
    const float* Wa = W_ha + (size_t)kb * H_SZ + h;
    const float* Wv = W_hv + (size_t)kb * H_SZ + h;

    float aA = 0.f, aV = 0.f;
#pragma unroll 8
    for (int k = 0; k < 512; ++k) {
        aA = fmaf(ha_s[kb + k], Wa[(size_t)k * H_SZ], aA);
        aV = fmaf(pv_s[kb + k], Wv[(size_t)k * H_SZ], aV);
    }

    if (ks == 1) { redA[t & 127] = aA; redV[t & 127] = aV; }
    __syncthreads();
    if (ks == 0) {
        float s = aA + aV + redA[t] + redV[t] + b_ha[h] + b_hv[h] + b_v[h];
        base_g[(size_t)b * H_SZ + h] = s;
    }
}

// ---------------------------------------------------------------------------
// Kernel 3 (fused, R22-exact — best measured, total 271.8us): 1024 thr =
// 16 waves (2M x 8N), wave 64x64, acc[4][4]=64 AGPR + ~60 VGPR, 128-reg
// cap. A: bf16 LDS dbuf (verified swizzle), single-rA staging; B: register-
// direct 4 frags from L2-hot fragment-packed Wt4, WAR reloads; setprio on
// MFMA; 1 barrier per kstep. Score -> online softmax -> V accumulate.
// R24's micro-edits (no-setprio, prologue hoist) regressed 258->310us and
// are reverted.
// ---------------------------------------------------------------------------
__global__ __launch_bounds__(1024, 4) void k_fused(const float* __restrict__ imgs,
                                                   const unsigned short* __restrict__ Wt4,
                                                   const float* __restrict__ base_g,
                                                   const float* __restrict__ W_f,
                                                   float* __restrict__ out) {
    __shared__ __align__(16) short A_s[2][128 * 32];   // 2 x 8 KB
    __shared__ float att_part[8][128];
    __shared__ float e_s[128];
    __shared__ float scal_r;
    __shared__ float scal_l;

    const int b = blockIdx.x;
    const int t = threadIdx.x;
    const int lane = t & 63, w = t >> 6;
    const int wm = w >> 3, wn = w & 7;           // 2M x 8N wave grid
    const int lr = lane & 15, g = lane >> 4;

    const float* imgb = imgs + (size_t)b * A_RG * DVD;
    const char* Bp = (const char*)Wt4 + ((size_t)(wn * 4) * 64 + lane) * 16;

    float o0 = 0.f, o1 = 0.f;           // thread owns out cols 2t, 2t+1
    float m_run = -1e30f, l_run = 0.f;  // live in wave 0

    // ---- A staging map: thread -> local row t>>3, chunk t&7 (4 floats) ----
    const int arow = t >> 3, ac = t & 7;
    const unsigned awr = (unsigned)(arow * 64 +
        ((((ac >> 1) ^ ((arow ^ (arow >> 2)) & 3)) << 4) | ((ac & 1) << 3)));

    // ---- A fragment read addresses ----
    unsigned ard[4];
#pragma unroll
    for (int mf = 0; mf < 4; ++mf) {
        int r = wm * 64 + mf * 16 + lr;
        ard[mf] = (unsigned)(r * 64 + ((g ^ ((r ^ (r >> 2)) & 3)) << 4));
    }

    for (int at = 0; at < 2; ++at) {
        const bool last = (at == 1);
        const int m0 = at * 128;

        const float* Ag = imgb + (size_t)min(m0 + arow, A_RG - 1) * DVD + ac * 4;

        f32x4 acc[4][4] = {};
        f32x4 rA;
        s16x8 aF[4], bR[4];

        auto ldA = [&](int kt) {
            rA = *(const f32x4*)(Ag + (size_t)kt * 32);
        };
        auto wrA = [&](int buf) {
            u32x2 pk;
            pk[0] = cvt2(rA[0], rA[1]);
            pk[1] = cvt2(rA[2], rA[3]);
            *(u32x2*)((char*)A_s[buf] + awr) = pk;
        };
        auto ldB = [&](int kt) {
            const char* p = Bp + (size_t)kt * 32768;
#pragma unroll
            for (int n = 0; n < 4; ++n)
                bR[n] = *(const s16x8*)(p + n * 1024);
        };

        // ---- prologue: B(0), A(0)->LDS buf0 ----
        ldB(0);
        ldA(0);
        wrA(0);
        asm volatile("s_waitcnt lgkmcnt(0)" ::: "memory");
        __builtin_amdgcn_sched_barrier(0);
        __builtin_amdgcn_s_barrier();

        // ---- K loop: 1 barrier/kstep (R16-proven) ----
        for (int kt = 0; kt < NKT; ++kt) {
            if (kt + 1 < NKT) ldA(kt + 1);           // HBM, lands by wrA below
            const char* Ac = (const char*)A_s[kt & 1];
#pragma unroll
            for (int mf = 0; mf < 4; ++mf)
                aF[mf] = *(const s16x8*)(Ac + ard[mf]);
            __builtin_amdgcn_s_setprio(1);
#pragma unroll
            for (int mf = 0; mf < 4; ++mf)
#pragma unroll
                for (int n = 0; n < 4; ++n)
                    acc[mf][n] = __builtin_amdgcn_mfma_f32_16x16x32_bf16(
                        aF[mf], bR[n], acc[mf][n], 0, 0, 0);
            __builtin_amdgcn_s_setprio(0);
            if (kt + 1 < NKT) {
                ldB(kt + 1);                         // WAR reload, L2/L1
                wrA((kt + 1) & 1);                   // waits rA (auto vmcnt)
                asm volatile("s_waitcnt lgkmcnt(0)" ::: "memory");
                __builtin_amdgcn_sched_barrier(0);
                __builtin_amdgcn_s_barrier();
            }
        }

        // ---- score epilogue: this wave's 64 cols -> att_part[wn][row] ----
        {
            float wfv[4], bs[4];
#pragma unroll
            for (int n = 0; n < 4; ++n) {
                int col = wn * 64 + n * 16 + lr;
                wfv[n] = W_f[col];
                bs[n] = base_g[(size_t)b * H_SZ + col];
            }
#pragma unroll
            for (int mf = 0; mf < 4; ++mf) {
                float pj[4] = {0.f, 0.f, 0.f, 0.f};
#pragma unroll
                for (int n = 0; n < 4; ++n) {
                    float a0 = fmaxf(acc[mf][n][0] + bs[n], 0.f);
                    float a1 = fmaxf(acc[mf][n][1] + bs[n], 0.f);
                    float a2 = fmaxf(acc[mf][n][2] + bs[n], 0.f);
                    float a3 = fmaxf(acc[mf][n][3] + bs[n], 0.f);
                    pj[0] = fmaf(a0, wfv[n], pj[0]);
                    pj[1] = fmaf(a1, wfv[n], pj[1]);
                    pj[2] = fmaf(a2, wfv[n], pj[2]);
                    pj[3] = fmaf(a3, wfv[n], pj[3]);
                }
#pragma unroll
                for (int j = 0; j < 4; ++j) {
                    float s = pj[j];
                    s += __shfl_xor(s, 1);
                    s += __shfl_xor(s, 2);
                    s += __shfl_xor(s, 4);
                    s += __shfl_xor(s, 8);   // 16 lr-lanes of this row
                    if (lr == 0)
                        att_part[wn][wm * 64 + mf * 16 + g * 4 + j] = s;
                }
            }
        }
        __builtin_amdgcn_s_barrier();

        // ---- wave 0: online-softmax state update ----
        if (w == 0) {
            int gr0 = m0 + lane, gr1 = m0 + lane + 64;
            float s0, s1;
            {
                float a = 0.f, c = 0.f;
#pragma unroll
                for (int q = 0; q < 8; ++q) {
                    a += att_part[q][lane];
                    c += att_part[q][lane + 64];
                }
                s0 = (gr0 < A_RG) ? a : -1e30f;
                s1 = (gr1 < A_RG) ? c : -1e30f;
            }
            float mx = fmaxf(s0, s1);
            for (int d = 1; d < 64; d <<= 1) mx = fmaxf(mx, __shfl_xor(mx, d));
            float m_new = fmaxf(m_run, mx);
            float r = __expf(m_run - m_new);
            float e0 = __expf(s0 - m_new);
            float e1 = __expf(s1 - m_new);
            float es = e0 + e1;
            for (int d = 1; d < 64; d <<= 1) es += __shfl_xor(es, d);
            l_run = l_run * r + es;
            m_run = m_new;
            e_s[lane] = e0;
            e_s[lane + 64] = e1;
            if (lane == 0) {
                scal_r = r;
                if (last) scal_l = l_run;
            }
        }
        __builtin_amdgcn_s_barrier();

        // ---- V phase: o = o*r + sum_a e[a] * imgs[b, m0+a, 2t..2t+1] ----
        {
            float r = scal_r;
            o0 *= r; o1 *= r;
            const float2* vb = (const float2*)imgb + t;
            const int AV = last ? (A_RG - 128) : 128;   // 68 or 128
#pragma unroll 4
            for (int a = 0; a < AV; ++a) {
                float e = e_s[a];
                float2 v = vb[(size_t)(m0 + a) * (DVD / 2)];
                o0 = fmaf(e, v.x, o0);
                o1 = fmaf(e, v.y, o1);
            }
        }
        // cross-tile LDS hazards covered by tile1's prologue fences
        // (R13/R16-verified pattern).
    }

    // ---- finalize: out[b, 2t..2t+1] = o / l ----
    float linv = 1.0f / scal_l;
    float2 res = make_float2(o0 * linv, o1 * linv);
    ((float2*)(out + (size_t)b * DVD))[t] = res;
}

// ---------------------------------------------------------------------------
extern "C" void kernel_launch(void* const* d_in, const int* in_sizes, int n_in,
                              void* d_out, int out_size, void* d_ws, size_t ws_size,
                              hipStream_t stream) {
    const float* h_att   = (const float*)d_in[0];
    const float* prev_h2 = (const float*)d_in[1];
    const float* imgs    = (const float*)d_in[2];
    const float* W_v     = (const float*)d_in[3];
    const float* b_v     = (const float*)d_in[4];
    const float* W_ha    = (const float*)d_in[5];
    const float* b_ha    = (const float*)d_in[6];
    const float* W_hv    = (const float*)d_in[7];
    const float* b_hv    = (const float*)d_in[8];
    const float* W_f     = (const float*)d_in[9];
    // d_in[10] = b_f: softmax-invariant additive constant -> unused

    // ws layout: [0,2MB) Wt4 bf16 fragment-packed; [2MB,+512KB) base fp32
    unsigned short* Wt4 = (unsigned short*)d_ws;
    float* base_g = (float*)((char*)d_ws + (size_t)DVD * H_SZ * 2);
    float* out = (float*)d_out;

    hipLaunchKernelGGL(k_prepW, dim3(256), dim3(256), 0, stream, W_v, Wt4);
    hipLaunchKernelGGL(k_base, dim3(4, B_SZ), dim3(256), 0, stream,
                       h_att, prev_h2, W_ha, b_ha, W_hv, b_hv, b_v, base_g);
    hipLaunchKernelGGL(k_fused, dim3(B_SZ), dim3(1024), 0, stream,
                       imgs, Wt4, base_g, W_f, out);
}